// Round 1
// baseline (166.820 us; speedup 1.0000x reference)
//
#include <hip/hip_runtime.h>
#include <math.h>

#ifndef M_PI
#define M_PI 3.14159265358979323846
#endif

#define T_LEN   262144
#define NBATCH  64
#define STEP    171
#define NSEG    1531          // (262144-512)/171 + 1
#define NPAIR   766           // ceil(1531/2); last pair has zero imag segment
#define WPB     128           // waves per batch
#define HI_BIN  244           // exclusive upper band bin
#define WIN_POWER 203.4688    // exact: 512*0.54^2 + 256*0.46^2 (periodic hamming)
#define FS_D    3152.0

__device__ __forceinline__ int bitrev3(int r) {
    return ((r & 1) << 2) | (r & 2) | ((r & 4) >> 2);
}
__device__ __forceinline__ int bitrev6(int v) {
    return ((v & 1) << 5) | ((v & 2) << 3) | ((v & 4) << 1) |
           ((v & 8) >> 1) | ((v & 16) >> 3) | ((v & 32) >> 5);
}

// ws float layout: [0,512) permuted weights Wp, [512,1024) window, [1024,1088) band acc
__global__ void init_tables_k(float* __restrict__ ws) {
    int t = threadIdx.x; // 512 threads
    // periodic Hamming window (natural order)
    ws[512 + t] = 0.54f - 0.46f * cosf((float)(2.0 * M_PI) * (float)t * (1.0f / 512.0f));
    // permuted, symmetrized, fully-folded A-weight table:
    // main kernel's (lane L, reg r) holds bin k = bitrev3(r) + 8*bitrev6(L)
    int r = t >> 6, L = t & 63;
    int k = bitrev3(r) + 8 * bitrev6(L);
    int m = (k <= 256) ? k : 512 - k;   // mirror to one-sided bin
    float wgt = 0.0f;
    if (m >= 1 && m < HI_BIN) {
        double f = (double)m * (FS_D / 512.0);
        const double f1 = 20.6, f2 = 107.7, f3 = 737.9, f4 = 12194.0;
        double fsq = f * f;
        double num = (f4 * f4) * fsq * fsq;
        double den = (fsq + f1 * f1) * sqrt(fsq + f2 * f2) * sqrt(fsq + f3 * f3) * (fsq + f4 * f4);
        double A = 20.0 * log10(num / den) + 2.0;      // - A1000, A1000 = -2
        double aw = pow(10.0, A * 0.1);
        // folds: one-sided 2x cancels pair /2; /win_power /FS /nseg (mean)
        wgt = (float)(aw / (WIN_POWER * FS_D * (double)NSEG));
    }
    ws[t] = wgt;
    if (t < NBATCH) ws[1024 + t] = 0.0f;
}

__global__ __launch_bounds__(256) void fft_band_k(const float* __restrict__ x,
                                                  float* __restrict__ ws) {
    const float* __restrict__ Wp   = ws;
    const float* __restrict__ wtab = ws + 512;
    float* band = ws + 1024;

    const int lane   = threadIdx.x & 63;
    const int waveId = (int)(blockIdx.x * 256 + threadIdx.x) >> 6;
    const int b      = waveId >> 7;           // / WPB
    const int winb   = waveId & (WPB - 1);

    // ---- per-wave constants (hoisted out of the segment loop) ----
    float wv[8], wt[8];
#pragma unroll
    for (int r = 0; r < 8; ++r) {
        wv[r] = wtab[lane + 64 * r];   // window for sample n = lane + 64r
        wt[r] = Wp[r * 64 + lane];     // weight for this (lane, reg)'s output bin
    }
    // mid twiddles e^{-2pi i * bitrev3(r) * lane / 512}
    float mre[8], mim[8];
#pragma unroll
    for (int r = 0; r < 8; ++r) {
        int k2 = bitrev3(r);
        float ang = (float)(-2.0 * M_PI / 512.0) * (float)(k2 * lane);
        float s, c;
        sincosf(ang, &s, &c);
        mre[r] = c; mim[r] = s;
    }
    // cross-lane stage twiddles: stage st, m = 32>>st, tw = e^{-i*pi*(lane&(m-1))/m}
    // only applied on upper lanes (lane&m); identity (1,0) on lower lanes.
    float sre[6], sim[6], sgn[6];
#pragma unroll
    for (int st = 0; st < 6; ++st) {
        int m = 32 >> st;
        if (lane & m) {
            float ang = (float)(-M_PI) * (float)(lane & (m - 1)) / (float)m;
            float s, c;
            sincosf(ang, &s, &c);
            sre[st] = c; sim[st] = s; sgn[st] = -1.0f;
        } else {
            sre[st] = 1.0f; sim[st] = 0.0f; sgn[st] = 1.0f;
        }
    }

    const float C707 = 0.70710678118654752f;
    float acc = 0.0f;
    const float* xb = x + (size_t)b * T_LEN;

    for (int p = winb; p < NPAIR; p += WPB) {
        const int s0 = 2 * p, s1 = 2 * p + 1;
        float zre[8], zim[8];
        const float* p0 = xb + s0 * STEP + lane;
#pragma unroll
        for (int r = 0; r < 8; ++r) zre[r] = p0[64 * r] * wv[r];
        if (s1 < NSEG) {                         // wave-uniform branch
            const float* p1 = xb + s1 * STEP + lane;
#pragma unroll
            for (int r = 0; r < 8; ++r) zim[r] = p1[64 * r] * wv[r];
        } else {
#pragma unroll
            for (int r = 0; r < 8; ++r) zim[r] = 0.0f;
        }

        // ---- per-lane radix-2 DIF FFT-8 over registers (n2 axis) ----
        float tre, tim;
        // stage m=4: pairs (i, i+4), tw = e^{-2pi i * i/8}
        tre = zre[0] - zre[4]; tim = zim[0] - zim[4];
        zre[0] += zre[4]; zim[0] += zim[4];
        zre[4] = tre; zim[4] = tim;                               // tw = 1
        tre = zre[1] - zre[5]; tim = zim[1] - zim[5];
        zre[1] += zre[5]; zim[1] += zim[5];
        zre[5] = C707 * (tre + tim); zim[5] = C707 * (tim - tre); // tw = (c,-c)
        tre = zre[2] - zre[6]; tim = zim[2] - zim[6];
        zre[2] += zre[6]; zim[2] += zim[6];
        zre[6] = tim; zim[6] = -tre;                              // tw = -i
        tre = zre[3] - zre[7]; tim = zim[3] - zim[7];
        zre[3] += zre[7]; zim[3] += zim[7];
        zre[7] = C707 * (tim - tre); zim[7] = -C707 * (tre + tim);// tw = (-c,-c)
        // stage m=2: groups {0..3},{4..7}; tw in {1, -i}
        tre = zre[0] - zre[2]; tim = zim[0] - zim[2];
        zre[0] += zre[2]; zim[0] += zim[2];
        zre[2] = tre; zim[2] = tim;
        tre = zre[1] - zre[3]; tim = zim[1] - zim[3];
        zre[1] += zre[3]; zim[1] += zim[3];
        zre[3] = tim; zim[3] = -tre;
        tre = zre[4] - zre[6]; tim = zim[4] - zim[6];
        zre[4] += zre[6]; zim[4] += zim[6];
        zre[6] = tre; zim[6] = tim;
        tre = zre[5] - zre[7]; tim = zim[5] - zim[7];
        zre[5] += zre[7]; zim[5] += zim[7];
        zre[7] = tim; zim[7] = -tre;
        // stage m=1: adjacent pairs, tw = 1
#pragma unroll
        for (int g = 0; g < 8; g += 2) {
            tre = zre[g] - zre[g + 1]; tim = zim[g] - zim[g + 1];
            zre[g] += zre[g + 1]; zim[g] += zim[g + 1];
            zre[g + 1] = tre; zim[g + 1] = tim;
        }

        // ---- mid twiddle: z[r] *= e^{-2pi i * bitrev3(r) * lane / 512} ----
#pragma unroll
        for (int r = 1; r < 8; ++r) {
            float a = zre[r] * mre[r] - zim[r] * mim[r];
            zim[r] = zre[r] * mim[r] + zim[r] * mre[r];
            zre[r] = a;
        }

        // ---- cross-lane radix-2 DIF FFT-64 per register + weighted energy ----
#pragma unroll
        for (int r = 0; r < 8; ++r) {
            float re = zre[r], im = zim[r];
#pragma unroll
            for (int st = 0; st < 6; ++st) {
                const int m = 32 >> st;
                float ore = __shfl_xor(re, m, 64);
                float oim = __shfl_xor(im, m, 64);
                // lower lane: a+b ; upper lane: (a-b)*tw  (tw stored as identity on lower)
                float nre = ore + sgn[st] * re;
                float nim = oim + sgn[st] * im;
                re = nre * sre[st] - nim * sim[st];
                im = nre * sim[st] + nim * sre[st];
            }
            acc += wt[r] * (re * re + im * im);
        }
    }

    // wave reduction, one atomic per wave
#pragma unroll
    for (int off = 32; off >= 1; off >>= 1) acc += __shfl_xor(acc, off, 64);
    if (lane == 0) atomicAdd(&band[b], acc);
}

__global__ void finalize_k(const float* __restrict__ ws, float* __restrict__ out) {
    int lane = threadIdx.x;  // 64 threads
    float lv = 10.0f * log10f(ws[1024 + lane]);
#pragma unroll
    for (int off = 32; off >= 1; off >>= 1) lv += __shfl_xor(lv, off, 64);
    if (lane == 0) out[0] = lv * (1.0f / 64.0f);
}

extern "C" void kernel_launch(void* const* d_in, const int* in_sizes, int n_in,
                              void* d_out, int out_size, void* d_ws, size_t ws_size,
                              hipStream_t stream) {
    const float* x = (const float*)d_in[0];
    float* out = (float*)d_out;
    float* ws  = (float*)d_ws;
    init_tables_k<<<1, 512, 0, stream>>>(ws);
    fft_band_k<<<(NBATCH * WPB) / 4, 256, 0, stream>>>(x, ws);
    finalize_k<<<1, 64, 0, stream>>>(ws, out);
}

// Round 2
// 118.128 us; speedup vs baseline: 1.4122x; 1.4122x over previous
//
#include <hip/hip_runtime.h>
#include <math.h>

#ifndef M_PI
#define M_PI 3.14159265358979323846
#endif

#define T_LEN   262144
#define NBATCH  64
#define STEP    171
#define NSEG    1531          // (262144-512)/171 + 1
#define NPAIR   766           // ceil(1531/2); last pair has zero imag segment
#define WPB     128           // waves per batch -> 8192 waves = 32/CU
#define HI_BIN  244           // exclusive upper band bin

__device__ __forceinline__ int bitrev3(int r) {
    return ((r & 1) << 2) | (r & 2) | ((r & 4) >> 2);
}

// VALU-pipe cross-lane helpers (gfx950)
__device__ __forceinline__ void pswap32(float& a, float& b) {
    asm volatile("v_permlane32_swap_b32 %0, %1" : "+v"(a), "+v"(b));
}
__device__ __forceinline__ void pswap16(float& a, float& b) {
    asm volatile("v_permlane16_swap_b32 %0, %1" : "+v"(a), "+v"(b));
}
template <int CTRL>
__device__ __forceinline__ float dppq(float x) {   // quad_perm DPP (VALU)
    return __int_as_float(__builtin_amdgcn_mov_dpp(__float_as_int(x), CTRL, 0xF, 0xF, true));
}
template <int OFF>
__device__ __forceinline__ float swz(float x) {    // ds_swizzle bit-mode (DS)
    return __int_as_float(__builtin_amdgcn_ds_swizzle(__float_as_int(x), OFF));
}

// ws layout: [0, 8192) per-wave partial band sums
__global__ __launch_bounds__(256) void fft_band_k(const float* __restrict__ x,
                                                  float* __restrict__ ws) {
    const int lane   = threadIdx.x & 63;
    const int waveId = (int)(blockIdx.x * 256 + threadIdx.x) >> 6;
    const int b      = waveId >> 7;           // / WPB
    const int winb   = waveId & (WPB - 1);
    const int L = lane;

    // ---- per-wave constants ----
    // window: n = lane + 64*r
    float wv[8];
#pragma unroll
    for (int r = 0; r < 8; ++r) {
        float n = (float)(L + 64 * r);
        wv[r] = 0.54f - 0.46f * __cosf((float)(2.0 * M_PI / 512.0) * n);
    }
    // folded A-weights at final (lane, reg p) position after the swap-trick FFT:
    // k = 4*L5 + 2*L4 + p2 + 8*(p0 + 2*p1 + 4*L3 + 8*L2 + 16*L1 + 32*L0)
    float wt[8];
#pragma unroll
    for (int p = 0; p < 8; ++p) {
        int k = 4 * ((L >> 5) & 1) + 2 * ((L >> 4) & 1) + ((p >> 2) & 1)
              + 8 * ((p & 1) + 2 * ((p >> 1) & 1) + 4 * ((L >> 3) & 1)
                     + 8 * ((L >> 2) & 1) + 16 * ((L >> 1) & 1) + 32 * (L & 1));
        int mb = (k <= 256) ? k : 512 - k;
        float wgt = 0.0f;
        if (mb >= 1 && mb < HI_BIN) {
            float f   = (float)mb * (3152.0f / 512.0f);
            float fsq = f * f;
            float num = 1.48693636e8f * fsq * fsq;      // f4^2 * f^4
            float d1  = fsq + 424.36f;                  // 20.6^2
            float d2  = fsq + 11599.29f;                // 107.7^2
            float d3  = fsq + 544496.41f;               // 737.9^2
            float d4  = fsq + 1.48693636e8f;            // 12194^2
            float ratio = (num / (d1 * d4)) * rsqrtf(d2 * d3);
            // 10^(A/10) = ratio^2 * 10^0.2 ; fold /(win_power*FS*nseg)
            wgt = ratio * ratio * 1.6141422e-9f;
        }
        wt[p] = wgt;
    }
    // mid twiddles e^{-2pi i * bitrev3(r) * lane / 512}
    float mre[8], mim[8];
#pragma unroll
    for (int r = 0; r < 8; ++r) {
        float ang = (float)(-2.0 * M_PI / 512.0) * (float)(bitrev3(r) * L);
        float s, c; __sincosf(ang, &s, &c);
        mre[r] = c; mim[r] = s;
    }
    // cross-lane stage twiddles
    float c32, s32, c16, s16;
    __sincosf((float)(-2.0 * M_PI) * (float)(L & 31) / 64.0f, &s32, &c32);
    __sincosf((float)(-2.0 * M_PI) * (float)(L & 15) / 32.0f, &s16, &c16);
    float c8, s8, g8, c4, s4, g4, c2, s2, g2, g1;
    if (L & 8) { __sincosf((float)(-2.0 * M_PI) * (float)(L & 7) / 16.0f, &s8, &c8); g8 = -1.0f; }
    else       { c8 = 1.0f; s8 = 0.0f; g8 = 1.0f; }
    if (L & 4) { __sincosf((float)(-2.0 * M_PI) * (float)(L & 3) / 8.0f, &s4, &c4); g4 = -1.0f; }
    else       { c4 = 1.0f; s4 = 0.0f; g4 = 1.0f; }
    if (L & 2) { c2 = (L & 1) ? 0.0f : 1.0f; s2 = (L & 1) ? -1.0f : 0.0f; g2 = -1.0f; }
    else       { c2 = 1.0f; s2 = 0.0f; g2 = 1.0f; }
    g1 = (L & 1) ? -1.0f : 1.0f;

    const float C707 = 0.70710678118654752f;
    float acc = 0.0f;
    const float* xb = x + (size_t)b * T_LEN;

    for (int p = winb; p < NPAIR; p += WPB) {
        const int s0 = 2 * p, s1 = 2 * p + 1;
        float zre[8], zim[8];
        const float* p0 = xb + s0 * STEP + L;
#pragma unroll
        for (int r = 0; r < 8; ++r) zre[r] = p0[64 * r] * wv[r];
        if (s1 < NSEG) {                         // wave-uniform branch
            const float* p1 = xb + s1 * STEP + L;
#pragma unroll
            for (int r = 0; r < 8; ++r) zim[r] = p1[64 * r] * wv[r];
        } else {
#pragma unroll
            for (int r = 0; r < 8; ++r) zim[r] = 0.0f;
        }

        // ---- per-lane radix-2 DIF FFT-8 over registers ----
        float tre, tim;
        tre = zre[0] - zre[4]; tim = zim[0] - zim[4];
        zre[0] += zre[4]; zim[0] += zim[4];
        zre[4] = tre; zim[4] = tim;
        tre = zre[1] - zre[5]; tim = zim[1] - zim[5];
        zre[1] += zre[5]; zim[1] += zim[5];
        zre[5] = C707 * (tre + tim); zim[5] = C707 * (tim - tre);
        tre = zre[2] - zre[6]; tim = zim[2] - zim[6];
        zre[2] += zre[6]; zim[2] += zim[6];
        zre[6] = tim; zim[6] = -tre;
        tre = zre[3] - zre[7]; tim = zim[3] - zim[7];
        zre[3] += zre[7]; zim[3] += zim[7];
        zre[7] = C707 * (tim - tre); zim[7] = -C707 * (tre + tim);
        tre = zre[0] - zre[2]; tim = zim[0] - zim[2];
        zre[0] += zre[2]; zim[0] += zim[2];
        zre[2] = tre; zim[2] = tim;
        tre = zre[1] - zre[3]; tim = zim[1] - zim[3];
        zre[1] += zre[3]; zim[1] += zim[3];
        zre[3] = tim; zim[3] = -tre;
        tre = zre[4] - zre[6]; tim = zim[4] - zim[6];
        zre[4] += zre[6]; zim[4] += zim[6];
        zre[6] = tre; zim[6] = tim;
        tre = zre[5] - zre[7]; tim = zim[5] - zim[7];
        zre[5] += zre[7]; zim[5] += zim[7];
        zre[7] = tim; zim[7] = -tre;
#pragma unroll
        for (int g = 0; g < 8; g += 2) {
            tre = zre[g] - zre[g + 1]; tim = zim[g] - zim[g + 1];
            zre[g] += zre[g + 1]; zim[g] += zim[g + 1];
            zre[g + 1] = tre; zim[g + 1] = tim;
        }

        // ---- mid twiddle ----
#pragma unroll
        for (int r = 1; r < 8; ++r) {
            float a = zre[r] * mre[r] - zim[r] * mim[r];
            zim[r] = zre[r] * mim[r] + zim[r] * mre[r];
            zre[r] = a;
        }

        // ---- cross-lane FFT-64 ----
        // stage m=32: permlane32_swap two-reg trick (VALU pipe)
#pragma unroll
        for (int q = 0; q < 8; q += 2) {
            pswap32(zre[q], zre[q + 1]);
            pswap32(zim[q], zim[q + 1]);
            float sr = zre[q] + zre[q + 1], si = zim[q] + zim[q + 1];
            float dr = zre[q] - zre[q + 1], di = zim[q] - zim[q + 1];
            zre[q] = sr; zim[q] = si;
            zre[q + 1] = dr * c32 - di * s32;
            zim[q + 1] = dr * s32 + di * c32;
        }
        // stage m=16: permlane16_swap trick, pairs (q, q+2)
        {
            const int qs[4] = {0, 1, 4, 5};
#pragma unroll
            for (int t = 0; t < 4; ++t) {
                const int q = qs[t];
                pswap16(zre[q], zre[q + 2]);
                pswap16(zim[q], zim[q + 2]);
                float sr = zre[q] + zre[q + 2], si = zim[q] + zim[q + 2];
                float dr = zre[q] - zre[q + 2], di = zim[q] - zim[q + 2];
                zre[q] = sr; zim[q] = si;
                zre[q + 2] = dr * c16 - di * s16;
                zim[q + 2] = dr * s16 + di * c16;
            }
        }
        // stages m=8, m=4: ds_swizzle (only remaining DS traffic)
#pragma unroll
        for (int q = 0; q < 8; ++q) {
            float pr = swz<0x201F>(zre[q]), pi = swz<0x201F>(zim[q]);
            float nr = fmaf(g8, zre[q], pr), ni = fmaf(g8, zim[q], pi);
            zre[q] = nr * c8 - ni * s8; zim[q] = nr * s8 + ni * c8;
        }
#pragma unroll
        for (int q = 0; q < 8; ++q) {
            float pr = swz<0x101F>(zre[q]), pi = swz<0x101F>(zim[q]);
            float nr = fmaf(g4, zre[q], pr), ni = fmaf(g4, zim[q], pi);
            zre[q] = nr * c4 - ni * s4; zim[q] = nr * s4 + ni * c4;
        }
        // stage m=2: quad_perm [2,3,0,1] DPP (VALU)
#pragma unroll
        for (int q = 0; q < 8; ++q) {
            float pr = dppq<0x4E>(zre[q]), pi = dppq<0x4E>(zim[q]);
            float nr = fmaf(g2, zre[q], pr), ni = fmaf(g2, zim[q], pi);
            zre[q] = nr * c2 - ni * s2; zim[q] = nr * s2 + ni * c2;
        }
        // stage m=1: quad_perm [1,0,3,2] DPP, twiddle == 1
#pragma unroll
        for (int q = 0; q < 8; ++q) {
            float pr = dppq<0xB1>(zre[q]), pi = dppq<0xB1>(zim[q]);
            float nr = fmaf(g1, zre[q], pr), ni = fmaf(g1, zim[q], pi);
            acc = fmaf(wt[q], fmaf(nr, nr, ni * ni), acc);
        }
    }

    // wave reduction, one slot per wave (no pre-zeroed memory needed)
#pragma unroll
    for (int off = 32; off >= 1; off >>= 1) acc += __shfl_xor(acc, off, 64);
    if (lane == 0) ws[waveId] = acc;
}

__global__ void finalize_k(const float* __restrict__ ws, float* __restrict__ out) {
    __shared__ float red[256];
    int t = threadIdx.x;          // 256 threads
    int b = t & 63, g = t >> 6;   // 4 chunks of 32 partials per batch
    float s = 0.0f;
    for (int i = 0; i < 32; ++i) s += ws[b * 128 + g * 32 + i];
    red[t] = s;
    __syncthreads();
    if (t < 64) {
        float band = red[t] + red[t + 64] + red[t + 128] + red[t + 192];
        float lv = 10.0f * log10f(band);
#pragma unroll
        for (int off = 32; off >= 1; off >>= 1) lv += __shfl_xor(lv, off, 64);
        if (t == 0) out[0] = lv * (1.0f / 64.0f);
    }
}

extern "C" void kernel_launch(void* const* d_in, const int* in_sizes, int n_in,
                              void* d_out, int out_size, void* d_ws, size_t ws_size,
                              hipStream_t stream) {
    const float* x = (const float*)d_in[0];
    float* out = (float*)d_out;
    float* ws  = (float*)d_ws;
    fft_band_k<<<(NBATCH * WPB) / 4, 256, 0, stream>>>(x, ws);
    finalize_k<<<1, 256, 0, stream>>>(ws, out);
}